// Round 1
// baseline (460.110 us; speedup 1.0000x reference)
//
#include <hip/hip_runtime.h>
#include <hip/hip_bf16.h>
#include <stdint.h>

#define B_    4
#define S_    2048
#define HID_  1024
#define NH_   8
#define L_    64
#define A_    64
#define NB_   128

using bf16 = __hip_bfloat16;
typedef __bf16 bf16x8 __attribute__((ext_vector_type(8)));
typedef float  f32x4  __attribute__((ext_vector_type(4)));

__device__ __forceinline__ float bf2f(bf16 v){ return __bfloat162float(v); }
__device__ __forceinline__ bf16  f2bf(float v){ return __float2bfloat16(v); }

__device__ __forceinline__ f32x4 mfma16(bf16x8 a, bf16x8 b, f32x4 c){
  return __builtin_amdgcn_mfma_f32_16x16x32_bf16(a, b, c, 0, 0, 0);
}

// async global->LDS, 16B per lane; LDS dest must be uniform_base + lane*16
__device__ __forceinline__ void gll16(const void* g, void* l){
  __builtin_amdgcn_global_load_lds(
      (const __attribute__((address_space(1))) unsigned int*)g,
      (__attribute__((address_space(3))) unsigned int*)l, 16, 0, 0);
}

// ---------------- transpose + cast f32[R][C] -> bf16[C][R] ----------------
__global__ __launch_bounds__(256) void k_tcast(const float* __restrict__ src,
                                               bf16* __restrict__ dst, int R, int C){
  __shared__ float t[32][33];
  int c0 = blockIdx.x*32, r0 = blockIdx.y*32;
  int tx = threadIdx.x & 31, ty = threadIdx.x >> 5;
#pragma unroll
  for (int j=0;j<4;j++) t[ty+j*8][tx] = src[(size_t)(r0+ty+j*8)*C + c0+tx];
  __syncthreads();
#pragma unroll
  for (int j=0;j<4;j++) dst[(size_t)(c0+ty+j*8)*R + r0+tx] = f2bf(t[tx][ty+j*8]);
}

// ---------------- rb4: the 4 possible FiLM rows ----------------
__global__ void k_rb4(const float* __restrict__ act_tab, const float* __restrict__ fg,
                      const float* __restrict__ fb, const float* __restrict__ fw,
                      const float* __restrict__ fbias, float* __restrict__ rb4){
  __shared__ float lnae[4][32];
  __shared__ float mv[4][2];
  int tid = threadIdx.x;
  if (tid < 128) lnae[tid>>5][tid&31] = act_tab[tid];
  __syncthreads();
  if (tid < 4){
    float s=0.f, q=0.f;
#pragma unroll
    for (int i=0;i<32;i++){ float a=lnae[tid][i]; s+=a; q+=a*a; }
    float mean = s*(1.f/32.f);
    mv[tid][0] = mean;
    mv[tid][1] = rsqrtf(q*(1.f/32.f) - mean*mean + 1e-5f);
  }
  __syncthreads();
  if (tid < 128){
    int id=tid>>5, i=tid&31;
    lnae[id][i] = (lnae[id][i]-mv[id][0])*mv[id][1]*fg[i] + fb[i];
  }
  __syncthreads();
  for (int idx=tid; idx<4*2048; idx+=256){
    int id = idx>>11, j = idx&2047;
    float acc = fbias[j];
#pragma unroll
    for (int i=0;i<32;i++) acc += lnae[id][i]*fw[i*2048+j];
    rb4[idx] = acc;
  }
}

// ---------------- LN(x) -> h (bf16) ----------------
__global__ __launch_bounds__(256) void k_ln_x(const float* __restrict__ x,
      const float* __restrict__ g, const float* __restrict__ bta, bf16* __restrict__ h){
  int row = blockIdx.x; int tid = threadIdx.x;
  const float* xr = x + (size_t)row*HID_;
  float v[4]; float sum=0.f, sq=0.f;
#pragma unroll
  for (int i=0;i<4;i++){ v[i]=xr[tid + i*256]; sum+=v[i]; sq+=v[i]*v[i]; }
#pragma unroll
  for (int o=1;o<64;o<<=1){ sum+=__shfl_xor(sum,o,64); sq+=__shfl_xor(sq,o,64); }
  __shared__ float red[2][4];
  int wid=tid>>6, lane=tid&63;
  if(lane==0){ red[0][wid]=sum; red[1][wid]=sq; }
  __syncthreads();
  sum = red[0][0]+red[0][1]+red[0][2]+red[0][3];
  sq  = red[1][0]+red[1][1]+red[1][2]+red[1][3];
  float mean = sum*(1.f/HID_);
  float rstd = rsqrtf(sq*(1.f/HID_)-mean*mean + 1e-5f);
#pragma unroll
  for (int i=0;i<4;i++){
    int c = tid+i*256;
    h[(size_t)row*HID_ + c] = f2bf((v[i]-mean)*rstd*g[c] + bta[c]);
  }
}

// ---------------- GEMM h[8192,1024] @ uvqkT^T -> silu -> proj bf16 ----------------
__global__ __launch_bounds__(256) void k_gemm_uvqk(const bf16* __restrict__ hb,
        const bf16* __restrict__ wT, bf16* __restrict__ proj){
  __shared__ __align__(16) ushort shA[128*32];
  __shared__ __align__(16) ushort shB[128*32];
  const int K = 1024;
  int bx = blockIdx.x;
  int tm = bx & 63, tn = bx >> 6;       // 64 x 16 tiles
  int brow = tm*128, bcol = tn*128;
  int tid = threadIdx.x;
  int wid = tid>>6, lane = tid&63, lr = lane&15, lg = lane>>4;
  int wm = wid>>1, wn = wid&1;
  f32x4 acc[4][4] = {};
  for (int k0=0; k0<K; k0+=32){
    __syncthreads();
#pragma unroll
    for (int i=0;i<2;i++){
      int c = tid + i*256;
      int row = c>>2, kp = (c&3)*8;
      gll16(&hb[(size_t)(brow+row)*K + k0+kp], &shA[c*8]);
      gll16(&wT[(size_t)(bcol+row)*K + k0+kp], &shB[c*8]);
    }
    __syncthreads();
    bf16x8 a[4], b[4];
#pragma unroll
    for (int m=0;m<4;m++) a[m] = *(const bf16x8*)&shA[(wm*64+m*16+lr)*32 + lg*8];
#pragma unroll
    for (int n=0;n<4;n++) b[n] = *(const bf16x8*)&shB[(wn*64+n*16+lr)*32 + lg*8];
#pragma unroll
    for (int m=0;m<4;m++)
#pragma unroll
      for (int n=0;n<4;n++)
        acc[m][n] = mfma16(a[m], b[n], acc[m][n]);
  }
#pragma unroll
  for (int m=0;m<4;m++)
#pragma unroll
    for (int n=0;n<4;n++)
#pragma unroll
      for (int r=0;r<4;r++){
        int row = brow + wm*64+m*16+lg*4+r;
        int col = bcol + wn*64+n*16+lr;
        float v = acc[m][n][r];
        proj[(size_t)row*2048 + col] = f2bf(v / (1.f + __expf(-v)));
      }
}

// ---------------- RoPE in place on Q,K blocks of proj ----------------
__global__ __launch_bounds__(256) void k_rope(bf16* __restrict__ proj){
  int row = blockIdx.x;                  // b*S + s
  int s = row & (S_-1);
  int t = threadIdx.x;
  int h = t >> 5, p = t & 31;
  const float L2_10000 = 13.287712379549449f;   // log2(10000)
  float inv = exp2f(-(float)p * (L2_10000/32.f));
  float f = (float)s * inv;
  float sn, c; sincosf(f, &sn, &c);
  size_t base = (size_t)row*2048;
  int cq = 1024 + h*64 + 2*p;
  float qe = bf2f(proj[base+cq]), qo = bf2f(proj[base+cq+1]);
  proj[base+cq]   = f2bf(qe*c - qo*sn);
  proj[base+cq+1] = f2bf(qo*c + qe*sn);
  int ck = 1536 + h*64 + 2*p;
  float ke = bf2f(proj[base+ck]), ko = bf2f(proj[base+ck+1]);
  proj[base+ck]   = f2bf(ke*c - ko*sn);
  proj[base+ck+1] = f2bf(ko*c + ke*sn);
}

// ---------------- V transpose: proj V block -> Vt[b*512+h*64+l][S] ----------------
__global__ __launch_bounds__(256) void k_vtrans(const bf16* __restrict__ proj, bf16* __restrict__ Vt){
  __shared__ __align__(16) ushort lds[32][520];
  int bx = blockIdx.x; int b = bx>>6; int s0 = (bx&63)*32;
  int tid = threadIdx.x;
#pragma unroll
  for (int i=0;i<8;i++){
    int c = tid + i*256;          // 0..2047
    int sl = c>>6, e8 = (c&63)*8;
    *(uint4*)&lds[sl][e8] = *(const uint4*)&proj[((size_t)(b*S_+s0+sl))*2048 + 512 + e8];
  }
  __syncthreads();
#pragma unroll
  for (int q=0;q<2;q++){
    int hl = tid + q*256;         // h*64+l
    ushort v[32];
#pragma unroll
    for (int j=0;j<32;j++) v[j] = lds[j][hl];
#pragma unroll
    for (int w=0;w<4;w++)
      *(uint4*)&Vt[((size_t)b*512 + hl)*S_ + s0 + w*8] = *(uint4*)&v[w*8];
  }
}

// ---------------- bias[b][s][t] = ts_w[bucket] + pos_w[t-s+S-1] ----------------
__global__ __launch_bounds__(256) void k_bias(const int* __restrict__ interval,
      const float* __restrict__ ts_w, const float* __restrict__ pos_w,
      bf16* __restrict__ biasg){
  size_t total = (size_t)B_*S_*S_;
  for (size_t idx = (size_t)blockIdx.x*blockDim.x + threadIdx.x; idx < total;
       idx += (size_t)gridDim.x*blockDim.x){
    int t = (int)(idx & (S_-1));
    int s = (int)((idx >> 11) & (S_-1));
    int b = (int)(idx >> 22);
    int sp = s+1; if (sp > S_-1) sp = S_-1;
    int i1 = interval[b*S_ + sp];
    int i0 = interval[b*S_ + t];
    float d = fmaxf(fabsf((float)(i1 - i0)), 1.f);
    int bk = (int)(logf(d) / 0.301f);
    bk = bk < 0 ? 0 : (bk > NB_ ? NB_ : bk);
    biasg[idx] = f2bf(ts_w[bk] + pos_w[t - s + (S_-1)]);
  }
}

// ---------------- fused causal attention (silu scores) + ln_na + U gate ----------------
__global__ __launch_bounds__(256) void k_attn(const bf16* __restrict__ proj,
     const bf16* __restrict__ Vt, const bf16* __restrict__ biasg,
     bf16* __restrict__ u_dot){
  __shared__ __align__(16) bf16 Plds[4][32][40];   // +8 pad vs bank conflicts
  int bx = blockIdx.x;
  int hh  = bx & 1;
  int b   = (bx>>1) & 3;
  int sti = bx >> 3;                                // 0..63
  int st  = (sti & 1) ? (63 - (sti>>1)) : (sti>>1); // big/small pairing for balance
  int s0 = st*32;
  int tid = threadIdx.x, wid = tid>>6, lane = tid&63, lr = lane&15, lg = lane>>4;
  int h = hh*4 + wid;
  size_t rowb = (size_t)b * S_;
  bf16x8 aq[2][2];
#pragma unroll
  for (int m=0;m<2;m++)
#pragma unroll
    for (int ks=0;ks<2;ks++)
      aq[m][ks] = *(const bf16x8*)&proj[(rowb + s0 + m*16 + lr)*2048 + 1024 + h*64 + ks*32 + lg*8];
  f32x4 acc[2][4] = {};
  int nT = (s0>>5) + 1;
  for (int it=0; it<nT; ++it){
    int t0 = it*32;
    bf16x8 bk[2][2];
#pragma unroll
    for (int n=0;n<2;n++)
#pragma unroll
      for (int ks=0;ks<2;ks++)
        bk[n][ks] = *(const bf16x8*)&proj[(rowb + t0 + n*16 + lr)*2048 + 1536 + h*64 + ks*32 + lg*8];
    f32x4 sacc[2][2] = {};
#pragma unroll
    for (int m=0;m<2;m++)
#pragma unroll
      for (int n=0;n<2;n++)
#pragma unroll
        for (int ks=0;ks<2;ks++)
          sacc[m][n] = mfma16(aq[m][ks], bk[n][ks], sacc[m][n]);
    __syncthreads();   // previous iteration's P reads are done before overwrite
#pragma unroll
    for (int m=0;m<2;m++)
#pragma unroll
      for (int n=0;n<2;n++)
#pragma unroll
        for (int r=0;r<4;r++){
          int sl = m*16+lg*4+r, tl = n*16+lr;
          int sg = s0+sl, tg = t0+tl;
          float v = sacc[m][n][r] + bf2f(biasg[((size_t)b*S_ + sg)*S_ + tg]);
          float pv = (tg <= sg) ? (v / (1.f + __expf(-v))) * (1.f/(float)S_) : 0.f;
          Plds[wid][sl][tl] = f2bf(pv);
        }
    __syncthreads();   // P visible (intra-wave LDS ordering made safe)
    bf16x8 pa[2];
#pragma unroll
    for (int m=0;m<2;m++) pa[m] = *(const bf16x8*)&Plds[wid][m*16+lr][lg*8];
    bf16x8 bv[4];
#pragma unroll
    for (int n=0;n<4;n++)
      bv[n] = *(const bf16x8*)&Vt[((size_t)b*512 + h*64 + n*16+lr)*S_ + t0 + lg*8];
#pragma unroll
    for (int m=0;m<2;m++)
#pragma unroll
      for (int n=0;n<4;n++)
        acc[m][n] = mfma16(pa[m], bv[n], acc[m][n]);
  }
  // ln_na over the 64 l-dims, then * U, store u_dot
#pragma unroll
  for (int m=0;m<2;m++)
#pragma unroll
    for (int r=0;r<4;r++){
      float sum=0.f, sq=0.f;
#pragma unroll
      for (int n=0;n<4;n++){ float v=acc[m][n][r]; sum+=v; sq+=v*v; }
#pragma unroll
      for (int o=1;o<16;o<<=1){ sum += __shfl_xor(sum,o,64); sq += __shfl_xor(sq,o,64); }
      float mean = sum*(1.f/64.f);
      float var  = sq*(1.f/64.f) - mean*mean;
      float rstd = rsqrtf(var + 1e-5f);
      int sg = s0 + m*16 + lg*4 + r;
#pragma unroll
      for (int n=0;n<4;n++){
        int col = n*16+lr;
        float nv = (acc[m][n][r]-mean)*rstd;
        float u  = bf2f(proj[(rowb+sg)*2048 + h*64 + col]);
        u_dot[(rowb+sg)*512 + h*64+col] = f2bf(nv*u);
      }
    }
}

// ---------------- out GEMM: base = x + u_dot @ o_w + o_b (f32 out) ----------------
__global__ __launch_bounds__(256) void k_gemm_out(const bf16* __restrict__ ud,
        const bf16* __restrict__ wT, const float* __restrict__ x,
        const float* __restrict__ ob, float* __restrict__ out){
  __shared__ __align__(16) ushort shA[128*32];
  __shared__ __align__(16) ushort shB[128*32];
  const int K = 512;
  int bx = blockIdx.x;
  int tm = bx & 63, tn = bx >> 6;       // 64 x 8 tiles
  int brow = tm*128, bcol = tn*128;
  int tid = threadIdx.x;
  int wid = tid>>6, lane = tid&63, lr = lane&15, lg = lane>>4;
  int wm = wid>>1, wn = wid&1;
  f32x4 acc[4][4] = {};
  for (int k0=0; k0<K; k0+=32){
    __syncthreads();
#pragma unroll
    for (int i=0;i<2;i++){
      int c = tid + i*256;
      int row = c>>2, kp = (c&3)*8;
      gll16(&ud[(size_t)(brow+row)*K + k0+kp], &shA[c*8]);
      gll16(&wT[(size_t)(bcol+row)*K + k0+kp], &shB[c*8]);
    }
    __syncthreads();
    bf16x8 a[4], b[4];
#pragma unroll
    for (int m=0;m<4;m++) a[m] = *(const bf16x8*)&shA[(wm*64+m*16+lr)*32 + lg*8];
#pragma unroll
    for (int n=0;n<4;n++) b[n] = *(const bf16x8*)&shB[(wn*64+n*16+lr)*32 + lg*8];
#pragma unroll
    for (int m=0;m<4;m++)
#pragma unroll
      for (int n=0;n<4;n++)
        acc[m][n] = mfma16(a[m], b[n], acc[m][n]);
  }
#pragma unroll
  for (int m=0;m<4;m++)
#pragma unroll
    for (int n=0;n<4;n++)
#pragma unroll
      for (int r=0;r<4;r++){
        int row = brow + wm*64+m*16+lg*4+r;
        int col = bcol + wn*64+n*16+lr;
        out[(size_t)row*HID_ + col] = acc[m][n][r] + x[(size_t)row*HID_ + col] + ob[col];
      }
}

// ---------------- FiLM residual (in place on d_out) ----------------
__global__ __launch_bounds__(256) void k_film(float* __restrict__ out,
   const float* __restrict__ rb4, const int* __restrict__ nat, const int* __restrict__ nm,
   const float* __restrict__ prg, const float* __restrict__ prb,
   const float* __restrict__ rsp, const float* __restrict__ bsp){
  int row = blockIdx.x; int tid = threadIdx.x;
  float* orow = out + (size_t)row*HID_;
  int id = (nat[row] + 1) * (nm[row]==1 ? 1 : 0);
  float rs = rsp[0], bs = bsp[0];
  float v[4]; float sum=0.f, sq=0.f;
#pragma unroll
  for (int i=0;i<4;i++){ v[i]=orow[tid+i*256]; sum+=v[i]; sq+=v[i]*v[i]; }
#pragma unroll
  for (int o=1;o<64;o<<=1){ sum+=__shfl_xor(sum,o,64); sq+=__shfl_xor(sq,o,64); }
  __shared__ float red[2][4];
  int wid=tid>>6, lane=tid&63;
  if(lane==0){ red[0][wid]=sum; red[1][wid]=sq; }
  __syncthreads();
  sum = red[0][0]+red[0][1]+red[0][2]+red[0][3];
  sq  = red[1][0]+red[1][1]+red[1][2]+red[1][3];
  float mean = sum*(1.f/HID_);
  float rstd = rsqrtf(sq*(1.f/HID_)-mean*mean + 1e-5f);
#pragma unroll
  for (int i=0;i<4;i++){
    int c = tid+i*256;
    float ln = (v[i]-mean)*rstd*prg[c]+prb[c];
    float r  = rb4[id*2048 + c];
    float b2 = rb4[id*2048 + 1024 + c];
    orow[c] = v[i] + ln*tanhf(r)*rs + b2*bs;
  }
}

extern "C" void kernel_launch(void* const* d_in, const int* in_sizes, int n_in,
                              void* d_out, int out_size, void* d_ws, size_t ws_size,
                              hipStream_t stream){
  const float* x        = (const float*)d_in[0];
  const int*   interval = (const int*)d_in[1];
  // d_in[2] attn_mask: deterministic causal tril -> recomputed, not read
  const int*   nat      = (const int*)d_in[3];
  const int*   nm       = (const int*)d_in[4];
  const float* ln_g     = (const float*)d_in[5];
  const float* ln_b     = (const float*)d_in[6];
  const float* uvqk     = (const float*)d_in[7];
  const float* o_w      = (const float*)d_in[8];
  const float* o_b      = (const float*)d_in[9];
  const float* pos_w    = (const float*)d_in[10];
  const float* ts_w     = (const float*)d_in[11];
  const float* act_tab  = (const float*)d_in[12];
  const float* film_g   = (const float*)d_in[13];
  const float* film_bt  = (const float*)d_in[14];
  const float* film_w   = (const float*)d_in[15];
  const float* film_b   = (const float*)d_in[16];
  const float* pr_g     = (const float*)d_in[17];
  const float* pr_b     = (const float*)d_in[18];
  const float* r_scale  = (const float*)d_in[19];
  const float* b_scale  = (const float*)d_in[20];
  float* out = (float*)d_out;

  char* ws = (char*)d_ws;
  bf16*  uvqkT = (bf16*)(ws);                      // [2048][1024]  4 MB
  bf16*  o_wT  = (bf16*)(ws + (4u<<20));           // [1024][512]   1 MB
  float* rb4   = (float*)(ws + (5u<<20));          // [4][2048]     32 KB
  bf16*  Vt    = (bf16*)(ws + (6u<<20));           // [B*512][2048] 8 MB (aliases hb, written after hb dead)
  bf16*  ud    = (bf16*)(ws + (14u<<20));          // [8192][512]   8 MB (aliases hb tail)
  bf16*  hb    = (bf16*)(ws + (6u<<20));           // [8192][1024] 16 MB -- NOTE: same region as Vt+ud
  bf16*  proj  = (bf16*)(ws + (22u<<20));          // [8192][2048] 32 MB
  bf16*  biasg = (bf16*)(ws + (54u<<20));          // [B][S][S]   33.5 MB  (total ~87.5 MB)

  k_tcast<<<dim3(2048/32, 1024/32), 256, 0, stream>>>(uvqk, uvqkT, 1024, 2048);
  k_tcast<<<dim3(1024/32,  512/32), 256, 0, stream>>>(o_w,  o_wT,   512, 1024);
  k_rb4<<<1, 256, 0, stream>>>(act_tab, film_g, film_bt, film_w, film_b, rb4);
  k_ln_x<<<B_*S_, 256, 0, stream>>>(x, ln_g, ln_b, hb);
  k_gemm_uvqk<<<64*16, 256, 0, stream>>>(hb, uvqkT, proj);
  k_rope<<<B_*S_, 256, 0, stream>>>(proj);
  k_vtrans<<<B_*64, 256, 0, stream>>>(proj, Vt);        // hb dead from here on
  k_bias<<<4096, 256, 0, stream>>>(interval, ts_w, pos_w, biasg);
  k_attn<<<512, 256, 0, stream>>>(proj, Vt, biasg, ud);
  k_gemm_out<<<64*8, 256, 0, stream>>>(ud, o_wT, x, o_b, out);
  k_film<<<B_*S_, 256, 0, stream>>>(out, rb4, nat, nm, pr_g, pr_b, r_scale, b_scale);
}

// Round 2
// 236.257 us; speedup vs baseline: 1.9475x; 1.9475x over previous
//
#include <hip/hip_runtime.h>
#include <hip/hip_bf16.h>
#include <stdint.h>

#define B_    4
#define S_    2048
#define HID_  1024
#define NH_   8
#define L_    64
#define A_    64
#define NB_   128

using bf16 = __hip_bfloat16;
typedef __bf16 bf16x8 __attribute__((ext_vector_type(8)));
typedef float  f32x4  __attribute__((ext_vector_type(4)));

__device__ __forceinline__ float bf2f(bf16 v){ return __bfloat162float(v); }
__device__ __forceinline__ bf16  f2bf(float v){ return __float2bfloat16(v); }

__device__ __forceinline__ f32x4 mfma16(bf16x8 a, bf16x8 b, f32x4 c){
  return __builtin_amdgcn_mfma_f32_16x16x32_bf16(a, b, c, 0, 0, 0);
}

// async global->LDS, 16B per lane; LDS dest must be uniform_base + lane*16
__device__ __forceinline__ void gll16(const void* g, void* l){
  __builtin_amdgcn_global_load_lds(
      (const __attribute__((address_space(1))) unsigned int*)g,
      (__attribute__((address_space(3))) unsigned int*)l, 16, 0, 0);
}

// ---------------- transpose + cast f32[R][C] -> bf16[C][R] ----------------
__global__ __launch_bounds__(256) void k_tcast(const float* __restrict__ src,
                                               bf16* __restrict__ dst, int R, int C){
  __shared__ float t[32][33];
  int c0 = blockIdx.x*32, r0 = blockIdx.y*32;
  int tx = threadIdx.x & 31, ty = threadIdx.x >> 5;
#pragma unroll
  for (int j=0;j<4;j++) t[ty+j*8][tx] = src[(size_t)(r0+ty+j*8)*C + c0+tx];
  __syncthreads();
#pragma unroll
  for (int j=0;j<4;j++) dst[(size_t)(c0+ty+j*8)*R + r0+tx] = f2bf(t[tx][ty+j*8]);
}

// ---------------- rb4: the 4 possible FiLM rows ----------------
__global__ void k_rb4(const float* __restrict__ act_tab, const float* __restrict__ fg,
                      const float* __restrict__ fb, const float* __restrict__ fw,
                      const float* __restrict__ fbias, float* __restrict__ rb4){
  __shared__ float lnae[4][32];
  __shared__ float mv[4][2];
  int tid = threadIdx.x;
  if (tid < 128) lnae[tid>>5][tid&31] = act_tab[tid];
  __syncthreads();
  if (tid < 4){
    float s=0.f, q=0.f;
#pragma unroll
    for (int i=0;i<32;i++){ float a=lnae[tid][i]; s+=a; q+=a*a; }
    float mean = s*(1.f/32.f);
    mv[tid][0] = mean;
    mv[tid][1] = rsqrtf(q*(1.f/32.f) - mean*mean + 1e-5f);
  }
  __syncthreads();
  if (tid < 128){
    int id=tid>>5, i=tid&31;
    lnae[id][i] = (lnae[id][i]-mv[id][0])*mv[id][1]*fg[i] + fb[i];
  }
  __syncthreads();
  for (int idx=tid; idx<4*2048; idx+=256){
    int id = idx>>11, j = idx&2047;
    float acc = fbias[j];
#pragma unroll
    for (int i=0;i<32;i++) acc += lnae[id][i]*fw[i*2048+j];
    rb4[idx] = acc;
  }
}

// ---------------- LN(x) -> h (bf16) ----------------
__global__ __launch_bounds__(256) void k_ln_x(const float* __restrict__ x,
      const float* __restrict__ g, const float* __restrict__ bta, bf16* __restrict__ h){
  int row = blockIdx.x; int tid = threadIdx.x;
  const float* xr = x + (size_t)row*HID_;
  float v[4]; float sum=0.f, sq=0.f;
#pragma unroll
  for (int i=0;i<4;i++){ v[i]=xr[tid + i*256]; sum+=v[i]; sq+=v[i]*v[i]; }
#pragma unroll
  for (int o=1;o<64;o<<=1){ sum+=__shfl_xor(sum,o,64); sq+=__shfl_xor(sq,o,64); }
  __shared__ float red[2][4];
  int wid=tid>>6, lane=tid&63;
  if(lane==0){ red[0][wid]=sum; red[1][wid]=sq; }
  __syncthreads();
  sum = red[0][0]+red[0][1]+red[0][2]+red[0][3];
  sq  = red[1][0]+red[1][1]+red[1][2]+red[1][3];
  float mean = sum*(1.f/HID_);
  float rstd = rsqrtf(sq*(1.f/HID_)-mean*mean + 1e-5f);
#pragma unroll
  for (int i=0;i<4;i++){
    int c = tid+i*256;
    h[(size_t)row*HID_ + c] = f2bf((v[i]-mean)*rstd*g[c] + bta[c]);
  }
}

// ---------------- GEMM h[8192,1024] @ uvqkT^T -> silu -> proj bf16 ----------------
__global__ __launch_bounds__(256) void k_gemm_uvqk(const bf16* __restrict__ hb,
        const bf16* __restrict__ wT, bf16* __restrict__ proj){
  __shared__ __align__(16) ushort shA[128*32];
  __shared__ __align__(16) ushort shB[128*32];
  const int K = 1024;
  int bx = blockIdx.x;
  int tm = bx & 63, tn = bx >> 6;       // 64 x 16 tiles
  int brow = tm*128, bcol = tn*128;
  int tid = threadIdx.x;
  int wid = tid>>6, lane = tid&63, lr = lane&15, lg = lane>>4;
  int wm = wid>>1, wn = wid&1;
  f32x4 acc[4][4] = {};
  for (int k0=0; k0<K; k0+=32){
    __syncthreads();
#pragma unroll
    for (int i=0;i<2;i++){
      int c = tid + i*256;
      int row = c>>2, kp = (c&3)*8;
      gll16(&hb[(size_t)(brow+row)*K + k0+kp], &shA[c*8]);
      gll16(&wT[(size_t)(bcol+row)*K + k0+kp], &shB[c*8]);
    }
    __syncthreads();
    bf16x8 a[4], b[4];
#pragma unroll
    for (int m=0;m<4;m++) a[m] = *(const bf16x8*)&shA[(wm*64+m*16+lr)*32 + lg*8];
#pragma unroll
    for (int n=0;n<4;n++) b[n] = *(const bf16x8*)&shB[(wn*64+n*16+lr)*32 + lg*8];
#pragma unroll
    for (int m=0;m<4;m++)
#pragma unroll
      for (int n=0;n<4;n++)
        acc[m][n] = mfma16(a[m], b[n], acc[m][n]);
  }
#pragma unroll
  for (int m=0;m<4;m++)
#pragma unroll
    for (int n=0;n<4;n++)
#pragma unroll
      for (int r=0;r<4;r++){
        int row = brow + wm*64+m*16+lg*4+r;
        int col = bcol + wn*64+n*16+lr;
        float v = acc[m][n][r];
        proj[(size_t)row*2048 + col] = f2bf(v / (1.f + __expf(-v)));
      }
}

// ---------------- RoPE in place on Q,K blocks of proj ----------------
__global__ __launch_bounds__(256) void k_rope(bf16* __restrict__ proj){
  int row = blockIdx.x;                  // b*S + s
  int s = row & (S_-1);
  int t = threadIdx.x;
  int h = t >> 5, p = t & 31;
  const float L2_10000 = 13.287712379549449f;   // log2(10000)
  float inv = exp2f(-(float)p * (L2_10000/32.f));
  float f = (float)s * inv;
  float sn, c; sincosf(f, &sn, &c);
  size_t base = (size_t)row*2048;
  int cq = 1024 + h*64 + 2*p;
  float qe = bf2f(proj[base+cq]), qo = bf2f(proj[base+cq+1]);
  proj[base+cq]   = f2bf(qe*c - qo*sn);
  proj[base+cq+1] = f2bf(qo*c + qe*sn);
  int ck = 1536 + h*64 + 2*p;
  float ke = bf2f(proj[base+ck]), ko = bf2f(proj[base+ck+1]);
  proj[base+ck]   = f2bf(ke*c - ko*sn);
  proj[base+ck+1] = f2bf(ko*c + ke*sn);
}

// ---------------- V transpose: proj V block -> Vt[b*512+h*64+l][S] ----------------
__global__ __launch_bounds__(256) void k_vtrans(const bf16* __restrict__ proj, bf16* __restrict__ Vt){
  __shared__ __align__(16) ushort lds[32][520];
  int bx = blockIdx.x; int b = bx>>6; int s0 = (bx&63)*32;
  int tid = threadIdx.x;
#pragma unroll
  for (int i=0;i<8;i++){
    int c = tid + i*256;          // 0..2047
    int sl = c>>6, e8 = (c&63)*8;
    *(uint4*)&lds[sl][e8] = *(const uint4*)&proj[((size_t)(b*S_+s0+sl))*2048 + 512 + e8];
  }
  __syncthreads();
#pragma unroll
  for (int q=0;q<2;q++){
    int hl = tid + q*256;         // h*64+l
    ushort v[32];
#pragma unroll
    for (int j=0;j<32;j++) v[j] = lds[j][hl];
#pragma unroll
    for (int w=0;w<4;w++)
      *(uint4*)&Vt[((size_t)b*512 + hl)*S_ + s0 + w*8] = *(uint4*)&v[w*8];
  }
}

// ---------------- fused causal attention (silu scores, inline bias) + ln_na + U gate --
// block = (st, b, h): bx = st*32 + b*8 + h. 4 waves split the t-tile range.
__global__ __launch_bounds__(256, 4) void k_attn(const bf16* __restrict__ proj,
     const bf16* __restrict__ Vt, const int* __restrict__ interval,
     const float* __restrict__ ts_w, const float* __restrict__ pos_w,
     bf16* __restrict__ u_dot){
  __shared__ __align__(16) bf16 Plds[4][32][36];     // per-wave P staging (pad 36)
  __shared__ float redbuf[4][16][65];                // cross-wave PV reduction
  int bx = blockIdx.x;
  int st = bx >> 5;                 // 0..63 -> CU-stride-256 gives st spread of 8
  int b  = (bx >> 3) & 3;
  int h  = bx & 7;
  int s0 = st*32;
  int tid = threadIdx.x, wid = tid>>6, lane = tid&63, lr = lane&15, lg = lane>>4;
  size_t rowb = (size_t)b * S_;
  const int* itv = interval + b*S_;

  // Q fragments (same for all 4 waves)
  bf16x8 aq[2][2];
#pragma unroll
  for (int m=0;m<2;m++)
#pragma unroll
    for (int ks=0;ks<2;ks++)
      aq[m][ks] = *(const bf16x8*)&proj[(rowb + s0 + m*16 + lr)*2048 + 1024 + h*64 + ks*32 + lg*8];

  // per-lane row-side interval values: rows sg = s0 + m*16 + lg*4 + r
  int iv1[2][4];
#pragma unroll
  for (int m=0;m<2;m++)
#pragma unroll
    for (int r=0;r<4;r++){
      int sg = s0 + m*16 + lg*4 + r;
      int sp = sg+1; if (sp > S_-1) sp = S_-1;
      iv1[m][r] = itv[sp];
    }

  f32x4 acc[2][4] = {};
  int nT = st + 1;
  for (int tt = wid; tt < nT; tt += 4){
    int t0 = tt*32;
    bf16x8 kb[2][2];
#pragma unroll
    for (int n=0;n<2;n++)
#pragma unroll
      for (int ks=0;ks<2;ks++)
        kb[n][ks] = *(const bf16x8*)&proj[(rowb + t0 + n*16 + lr)*2048 + 1536 + h*64 + ks*32 + lg*8];
    f32x4 sacc[2][2] = {};
#pragma unroll
    for (int m=0;m<2;m++)
#pragma unroll
      for (int n=0;n<2;n++)
#pragma unroll
        for (int ks=0;ks<2;ks++)
          sacc[m][n] = mfma16(aq[m][ks], kb[n][ks], sacc[m][n]);
    // bias + silu + causal mask -> P (bf16) into per-wave LDS
#pragma unroll
    for (int n=0;n<2;n++){
      int tg = t0 + n*16 + lr;
      int i0 = itv[tg];
#pragma unroll
      for (int m=0;m<2;m++)
#pragma unroll
        for (int r=0;r<4;r++){
          int sl = m*16 + lg*4 + r;
          int sg = s0 + sl;
          float d = fabsf((float)(iv1[m][r] - i0));
          d = fmaxf(d, 1.f);
          int bkt = (int)(__log2f(d) * 2.3027481f);
          bkt = bkt < 0 ? 0 : (bkt > NB_ ? NB_ : bkt);
          float v = sacc[m][n][r] + ts_w[bkt] + pos_w[tg - sg + (S_-1)];
          float p = v * __builtin_amdgcn_rcpf(1.f + __expf(-v)) * (1.f/(float)S_);
          Plds[wid][sl][n*16+lr] = f2bf(tg <= sg ? p : 0.f);
        }
    }
    // PV: P (A-frag) from LDS, V (B-frag) from Vt
    bf16x8 pa[2];
#pragma unroll
    for (int m=0;m<2;m++) pa[m] = *(const bf16x8*)&Plds[wid][m*16+lr][lg*8];
    bf16x8 bv[4];
#pragma unroll
    for (int n=0;n<4;n++)
      bv[n] = *(const bf16x8*)&Vt[((size_t)b*512 + h*64 + n*16+lr)*S_ + t0 + lg*8];
#pragma unroll
    for (int m=0;m<2;m++)
#pragma unroll
      for (int n=0;n<4;n++)
        acc[m][n] = mfma16(pa[m], bv[n], acc[m][n]);
  }

  // cross-wave reduction (two 16-row chunks) + ln_na + U gate
#pragma unroll
  for (int m=0;m<2;m++){
    __syncthreads();
#pragma unroll
    for (int n=0;n<4;n++)
#pragma unroll
      for (int r=0;r<4;r++)
        redbuf[wid][lg*4+r][n*16+lr] = acc[m][n][r];
    __syncthreads();
#pragma unroll
    for (int q=0;q<4;q++){
      int rr = wid*4 + q;
      float v = redbuf[0][rr][lane] + redbuf[1][rr][lane]
              + redbuf[2][rr][lane] + redbuf[3][rr][lane];
      float sum = v, sq = v*v;
#pragma unroll
      for (int o=1;o<64;o<<=1){ sum += __shfl_xor(sum,o,64); sq += __shfl_xor(sq,o,64); }
      float mean = sum*(1.f/64.f);
      float rstd = rsqrtf(sq*(1.f/64.f) - mean*mean + 1e-5f);
      int sg = s0 + m*16 + rr;
      float u = bf2f(proj[(rowb+sg)*2048 + h*64 + lane]);
      u_dot[(rowb+sg)*512 + h*64 + lane] = f2bf((v-mean)*rstd*u);
    }
  }
}

// ---------------- out GEMM: base = x + u_dot @ o_w + o_b (f32 out) ----------------
__global__ __launch_bounds__(256) void k_gemm_out(const bf16* __restrict__ ud,
        const bf16* __restrict__ wT, const float* __restrict__ x,
        const float* __restrict__ ob, float* __restrict__ out){
  __shared__ __align__(16) ushort shA[128*32];
  __shared__ __align__(16) ushort shB[128*32];
  const int K = 512;
  int bx = blockIdx.x;
  int tm = bx & 63, tn = bx >> 6;       // 64 x 8 tiles
  int brow = tm*128, bcol = tn*128;
  int tid = threadIdx.x;
  int wid = tid>>6, lane = tid&63, lr = lane&15, lg = lane>>4;
  int wm = wid>>1, wn = wid&1;
  f32x4 acc[4][4] = {};
  for (int k0=0; k0<K; k0+=32){
    __syncthreads();
#pragma unroll
    for (int i=0;i<2;i++){
      int c = tid + i*256;
      int row = c>>2, kp = (c&3)*8;
      gll16(&ud[(size_t)(brow+row)*K + k0+kp], &shA[c*8]);
      gll16(&wT[(size_t)(bcol+row)*K + k0+kp], &shB[c*8]);
    }
    __syncthreads();
    bf16x8 a[4], b[4];
#pragma unroll
    for (int m=0;m<4;m++) a[m] = *(const bf16x8*)&shA[(wm*64+m*16+lr)*32 + lg*8];
#pragma unroll
    for (int n=0;n<4;n++) b[n] = *(const bf16x8*)&shB[(wn*64+n*16+lr)*32 + lg*8];
#pragma unroll
    for (int m=0;m<4;m++)
#pragma unroll
      for (int n=0;n<4;n++)
        acc[m][n] = mfma16(a[m], b[n], acc[m][n]);
  }
#pragma unroll
  for (int m=0;m<4;m++)
#pragma unroll
    for (int n=0;n<4;n++)
#pragma unroll
      for (int r=0;r<4;r++){
        int row = brow + wm*64+m*16+lg*4+r;
        int col = bcol + wn*64+n*16+lr;
        out[(size_t)row*HID_ + col] = acc[m][n][r] + x[(size_t)row*HID_ + col] + ob[col];
      }
}

// ---------------- FiLM residual (in place on d_out) ----------------
__global__ __launch_bounds__(256) void k_film(float* __restrict__ out,
   const float* __restrict__ rb4, const int* __restrict__ nat, const int* __restrict__ nm,
   const float* __restrict__ prg, const float* __restrict__ prb,
   const float* __restrict__ rsp, const float* __restrict__ bsp){
  int row = blockIdx.x; int tid = threadIdx.x;
  float* orow = out + (size_t)row*HID_;
  int id = (nat[row] + 1) * (nm[row]==1 ? 1 : 0);
  float rs = rsp[0], bs = bsp[0];
  float v[4]; float sum=0.f, sq=0.f;
#pragma unroll
  for (int i=0;i<4;i++){ v[i]=orow[tid+i*256]; sum+=v[i]; sq+=v[i]*v[i]; }
#pragma unroll
  for (int o=1;o<64;o<<=1){ sum+=__shfl_xor(sum,o,64); sq+=__shfl_xor(sq,o,64); }
  __shared__ float red[2][4];
  int wid=tid>>6, lane=tid&63;
  if(lane==0){ red[0][wid]=sum; red[1][wid]=sq; }
  __syncthreads();
  sum = red[0][0]+red[0][1]+red[0][2]+red[0][3];
  sq  = red[1][0]+red[1][1]+red[1][2]+red[1][3];
  float mean = sum*(1.f/HID_);
  float rstd = rsqrtf(sq*(1.f/HID_)-mean*mean + 1e-5f);
#pragma unroll
  for (int i=0;i<4;i++){
    int c = tid+i*256;
    float ln = (v[i]-mean)*rstd*prg[c]+prb[c];
    float r  = rb4[id*2048 + c];
    float b2 = rb4[id*2048 + 1024 + c];
    orow[c] = v[i] + ln*tanhf(r)*rs + b2*bs;
  }
}

extern "C" void kernel_launch(void* const* d_in, const int* in_sizes, int n_in,
                              void* d_out, int out_size, void* d_ws, size_t ws_size,
                              hipStream_t stream){
  const float* x        = (const float*)d_in[0];
  const int*   interval = (const int*)d_in[1];
  // d_in[2] attn_mask: deterministic causal tril -> recomputed, not read
  const int*   nat      = (const int*)d_in[3];
  const int*   nm       = (const int*)d_in[4];
  const float* ln_g     = (const float*)d_in[5];
  const float* ln_b     = (const float*)d_in[6];
  const float* uvqk     = (const float*)d_in[7];
  const float* o_w      = (const float*)d_in[8];
  const float* o_b      = (const float*)d_in[9];
  const float* pos_w    = (const float*)d_in[10];
  const float* ts_w     = (const float*)d_in[11];
  const float* act_tab  = (const float*)d_in[12];
  const float* film_g   = (const float*)d_in[13];
  const float* film_bt  = (const float*)d_in[14];
  const float* film_w   = (const float*)d_in[15];
  const float* film_b   = (const float*)d_in[16];
  const float* pr_g     = (const float*)d_in[17];
  const float* pr_b     = (const float*)d_in[18];
  const float* r_scale  = (const float*)d_in[19];
  const float* b_scale  = (const float*)d_in[20];
  float* out = (float*)d_out;

  char* ws = (char*)d_ws;
  bf16*  uvqkT = (bf16*)(ws);                      // [2048][1024]  4 MB
  bf16*  o_wT  = (bf16*)(ws + (4u<<20));           // [1024][512]   1 MB
  float* rb4   = (float*)(ws + (5u<<20));          // [4][2048]     32 KB
  bf16*  hb    = (bf16*)(ws + (6u<<20));           // [8192][1024] 16 MB (dead after gemm_uvqk)
  bf16*  Vt    = (bf16*)(ws + (6u<<20));           // [B*512][2048] 8 MB (aliases hb)
  bf16*  ud    = (bf16*)(ws + (14u<<20));          // [8192][512]   8 MB (aliases hb tail)
  bf16*  proj  = (bf16*)(ws + (22u<<20));          // [8192][2048] 32 MB  (total 54 MB)

  k_tcast<<<dim3(2048/32, 1024/32), 256, 0, stream>>>(uvqk, uvqkT, 1024, 2048);
  k_tcast<<<dim3(1024/32,  512/32), 256, 0, stream>>>(o_w,  o_wT,   512, 1024);
  k_rb4<<<1, 256, 0, stream>>>(act_tab, film_g, film_bt, film_w, film_b, rb4);
  k_ln_x<<<B_*S_, 256, 0, stream>>>(x, ln_g, ln_b, hb);
  k_gemm_uvqk<<<64*16, 256, 0, stream>>>(hb, uvqkT, proj);
  k_rope<<<B_*S_, 256, 0, stream>>>(proj);
  k_vtrans<<<B_*64, 256, 0, stream>>>(proj, Vt);        // hb dead from here on
  k_attn<<<64*32, 256, 0, stream>>>(proj, Vt, interval, ts_w, pos_w, ud);
  k_gemm_out<<<64*8, 256, 0, stream>>>(ud, o_wT, x, o_b, out);
  k_film<<<B_*S_, 256, 0, stream>>>(out, rb4, nat, nm, pr_g, pr_b, r_scale, b_scale);
}